// Round 4
// baseline (242.678 us; speedup 1.0000x reference)
//
#include <hip/hip_runtime.h>
#include <hip/hip_bf16.h>
#include <stdint.h>

#define NB 32
#define NC 512
#define NP 576
#define NN 4096

typedef __attribute__((ext_vector_type(8))) short short8;
typedef __attribute__((ext_vector_type(4))) float floatx4;

static __device__ __forceinline__ short f2bf(float f) {
  union { __hip_bfloat16 h; short s; } u;
  u.h = __float2bfloat16(f);
  return u.s;
}

#define GLOAD_F32(dst, voff, sbase) \
  asm volatile("global_load_dword %0, %1, %2" : "=v"(dst) : "v"(voff), "s"(sbase))
#define GLOAD_B128(dst, voff, sbase) \
  asm volatile("global_load_dwordx4 %0, %1, %2" : "=v"(dst) : "v"(voff), "s"(sbase))
#define DSWRITE_B128(addr, data) \
  asm volatile("ds_write_b128 %0, %1" :: "v"(addr), "v"(data))
#define WAIT_VMCNT(N) asm volatile("s_waitcnt vmcnt(" #N ")" ::: "memory")
#define WAIT_LGKM0    asm volatile("s_waitcnt lgkmcnt(0)" ::: "memory")
#define SBAR() do { asm volatile("" ::: "memory"); __builtin_amdgcn_s_barrier(); asm volatile("" ::: "memory"); } while (0)
#define SCHEDBAR() __builtin_amdgcn_sched_barrier(0)

// ---------------- K1: inverse L2 norms over channel dim (patch only) ----------------
__global__ void norms_kernel(const float* __restrict__ in, float* __restrict__ invn,
                             int nsp, int total) {
  int idx = blockIdx.x * 256 + threadIdx.x;
  if (idx >= total) return;
  int b = idx / nsp, sp = idx - b * nsp;
  const float* p = in + (size_t)b * NC * nsp + sp;
  float s = 0.f;
#pragma unroll 8
  for (int c = 0; c < NC; ++c) { float v = p[(size_t)c * nsp]; s = fmaf(v, v, s); }
  invn[idx] = 1.0f / fmaxf(sqrtf(s), 1e-12f);
}

// ---------------- K2: transpose patch [C][P] -> [P][C], scale, bf16 ----------------
__global__ void transpose_kernel(const float* __restrict__ in, const float* __restrict__ invn,
                                 __hip_bfloat16* __restrict__ out, int nsp) {
  __shared__ float tile[64][65];
  int b = blockIdx.z, c0 = blockIdx.y * 64, p0 = blockIdx.x * 64;
  int tx = threadIdx.x & 63, ty = threadIdx.x >> 6;
  const float* src = in + ((size_t)b * NC + c0) * nsp + p0;
#pragma unroll
  for (int r = ty; r < 64; r += 4) tile[r][tx] = src[(size_t)r * nsp + tx];
  __syncthreads();
  __hip_bfloat16* dst = out + ((size_t)b * nsp + p0) * NC + c0;
#pragma unroll
  for (int r = ty; r < 64; r += 4) {
    float iv = invn[b * nsp + p0 + r];
    dst[(size_t)r * NC + tx] = __float2bfloat16(tile[tx][r] * iv);
  }
}

// ---------------- K3: fused GEMM + softmax-reduction ----------------
// Full M (576) x 64 j per block, K=512 in 16 steps of 32.
// Pipeline per iter t: issueA(t+1), issueG(t+2), MFMA(t) [no wait],
// vmcnt(17)->cvt/ds_write G(t+1), vmcnt(8)->A(t+1) home, lgkm0, barrier.
// A prefetch depth 1, G depth 2; never vmcnt(0) in the main loop.
__global__ __launch_bounds__(256, 2)
void affinity_kernel(const __hip_bfloat16* __restrict__ srcT,
                     const float* __restrict__ x,
                     float* __restrict__ partials) {
  const int bid = blockIdx.x;
  const int T = (bid & 7) * 256 + (bid >> 3);   // bijective XCD swizzle (2048 = 8*256)
  const int b = T >> 6, jc = T & 63;
  const int tid = threadIdx.x, lane = tid & 63, w = tid >> 6;
  const int g = lane >> 4, l15 = lane & 15;

  __shared__ __align__(16) char Bl[2][4096];
  __shared__ float red[4][64];
  __shared__ float invd[64];

  const uint64_t sA = (uint64_t)(uintptr_t)srcT;
  const uint64_t sX = (uint64_t)(uintptr_t)x;

  // A byte-offset base: row = w*144 + mi*16 + l15, col-bytes g*16, +mi*16384 +t*64
  const uint32_t vAbase = (uint32_t)(b * NP + w * 144 + l15) * (uint32_t)(NC * 2)
                        + (uint32_t)g * 16u;
  // G byte-offset base: k-row = w*8 + r, j = jc*64 + lane; +r*16384 +t*524288
  const uint32_t vGbase = (uint32_t)(b * NC + w * 8) * (uint32_t)(NN * 4)
                        + (uint32_t)(jc * 64 + lane) * 4u;

  const uint32_t ldsbase = (uint32_t)(uintptr_t)(&Bl[0][0]);
  const uint32_t wraddr = ldsbase + (uint32_t)w * 1024u + (uint32_t)lane * 16u;

  floatx4 acc[9][4];
#pragma unroll
  for (int mi = 0; mi < 9; ++mi)
#pragma unroll
    for (int ni = 0; ni < 4; ++ni) acc[mi][ni] = (floatx4){0.f, 0.f, 0.f, 0.f};

  short8 afA[9], afB[9];
  float GA[8], GB[8];
  float sq = 0.f;

  auto issueA = [&](int t, short8 (&af)[9]) {
#pragma unroll
    for (int mi = 0; mi < 9; ++mi) {
      uint32_t v = vAbase + (uint32_t)mi * 16384u + (uint32_t)t * 64u;
      GLOAD_B128(af[mi], v, sA);
    }
  };
  auto issueG = [&](int t, float (&Gv)[8]) {
#pragma unroll
    for (int r = 0; r < 8; ++r) {
      uint32_t v = vGbase + (uint32_t)r * (uint32_t)(NN * 4) + (uint32_t)t * (32u * NN * 4u);
      GLOAD_F32(Gv[r], v, sX);
    }
  };
  auto cvtWrite = [&](float (&Gv)[8], uint32_t slotoff) {
    short8 bf;
#pragma unroll
    for (int r = 0; r < 8; ++r) {
      sq = fmaf(Gv[r], Gv[r], sq);
      bf[r] = f2bf(Gv[r]);
    }
    DSWRITE_B128(wraddr + slotoff, bf);
  };
  auto mfmaStep = [&](uint32_t slotoff, short8 (&af)[9]) {
#pragma unroll
    for (int ni = 0; ni < 4; ++ni) {
      short8 bfr = *(const short8*)(&Bl[0][0] + slotoff + (uint32_t)g * 1024u
                                    + (uint32_t)ni * 256u + (uint32_t)l15 * 16u);
#pragma unroll
      for (int mi = 0; mi < 9; ++mi)
        acc[mi][ni] = __builtin_amdgcn_mfma_f32_16x16x32_bf16(af[mi], bfr, acc[mi][ni], 0, 0, 0);
    }
  };

  // ---- prologue: G0->GB, G1->GA, A0->afA; buf0 = B(0) ----
  issueG(0, GB);
  issueG(1, GA);
  issueA(0, afA);
  WAIT_VMCNT(0); SCHEDBAR();
  cvtWrite(GB, 0u);
  WAIT_LGKM0;
  SBAR();

  // ---- main loop: tiles 0..13, unrolled x2 ----
#pragma unroll 1
  for (int t = 0; t < 14; t += 2) {
    // even: consume tile t (buf0, afA); write buf1 = B(t+1) from GA
    issueA(t + 1, afB);
    issueG(t + 2, GB);
    mfmaStep(0u, afA);
    WAIT_VMCNT(17); SCHEDBAR();   // retire G(t+1) (GA); keep A(t+1)+G(t+2)
    cvtWrite(GA, 4096u);
    WAIT_VMCNT(8); SCHEDBAR();    // retire A(t+1) (afB); keep G(t+2)
    WAIT_LGKM0;
    SBAR();
    // odd: consume tile t+1 (buf1, afB); write buf0 = B(t+2) from GB
    issueA(t + 2, afA);
    issueG(t + 3, GA);
    mfmaStep(4096u, afB);
    WAIT_VMCNT(17); SCHEDBAR();   // retire G(t+2) (GB)
    cvtWrite(GB, 0u);
    WAIT_VMCNT(8); SCHEDBAR();    // retire A(t+2) (afA)
    WAIT_LGKM0;
    SBAR();
  }
  // ---- tail: tile 14 (buf0, afA); G15 is in flight -> GA ----
  issueA(15, afB);
  mfmaStep(0u, afA);
  WAIT_VMCNT(9); SCHEDBAR();      // retire G15 (GA); keep A15
  cvtWrite(GA, 4096u);
  WAIT_VMCNT(0); SCHEDBAR();      // retire A15 (afB)
  WAIT_LGKM0;
  SBAR();
  // ---- tail: tile 15 (buf1, afB) ----
  mfmaStep(4096u, afB);

  // ---- dst inv-norms from in-loop fp32 sumsq (lane's column j = lane) ----
  __syncthreads();
  red[w][lane] = sq;
  __syncthreads();
  if (tid < 64)
    invd[tid] = rsqrtf(fmaxf(red[0][tid] + red[1][tid] + red[2][tid] + red[3][tid], 1e-24f));
  __syncthreads();

  float iv[4], cxj[4];
#pragma unroll
  for (int ni = 0; ni < 4; ++ni) {
    iv[ni] = invd[ni * 16 + l15];
    cxj[ni] = (float)(ni * 16 + l15) + 0.5f;   // cx = (j & 63) + 0.5
  }

  // ---- exp + weighted reduction (cy = jc + 0.5 block-uniform) ----
#pragma unroll
  for (int mi = 0; mi < 9; ++mi) {
    float s[4] = {0.f, 0.f, 0.f, 0.f}, sx[4] = {0.f, 0.f, 0.f, 0.f};
#pragma unroll
    for (int ni = 0; ni < 4; ++ni)
#pragma unroll
      for (int r = 0; r < 4; ++r) {
        float p = __expf(acc[mi][ni][r] * iv[ni]);
        s[r] += p;
        sx[r] = fmaf(p, cxj[ni], sx[r]);
      }
#pragma unroll
    for (int r = 0; r < 4; ++r) {
#pragma unroll
      for (int m = 1; m < 16; m <<= 1) {
        s[r] += __shfl_xor(s[r], m);
        sx[r] += __shfl_xor(sx[r], m);
      }
    }
    if (l15 == 0) {
#pragma unroll
      for (int r = 0; r < 4; ++r) {
        int row = w * 144 + mi * 16 + g * 4 + r;
        float* o = partials + ((size_t)(b * NP + row) * 64 + jc) * 2;
        o[0] = s[r];
        o[1] = sx[r];
      }
    }
  }
}

// ---------------- K4: finalize ----------------
__global__ void finalize_kernel(const float* __restrict__ partials, float* __restrict__ out) {
  int b = blockIdx.x;
  int t = threadIdx.x;
  float sxt = 0.f, syt = 0.f;
  for (int i = t; i < NP; i += 256) {
    const float* p = partials + ((size_t)(b * NP + i) * 64) * 2;
    float s = 0.f, sx = 0.f, sy = 0.f;
#pragma unroll
    for (int jc2 = 0; jc2 < 64; ++jc2) {
      float ss = p[jc2 * 2];
      s += ss;
      sx += p[jc2 * 2 + 1];
      sy = fmaf(ss, (float)jc2 + 0.5f, sy);
    }
    sxt += sx / s;
    syt += sy / s;
  }
  __shared__ float rs[256], rs2[256];
  rs[t] = sxt; rs2[t] = syt;
  __syncthreads();
  for (int o = 128; o > 0; o >>= 1) {
    if (t < o) { rs[t] += rs[t + o]; rs2[t] += rs2[t + o]; }
    __syncthreads();
  }
  if (t == 0) {
    float cx = rs[0] / (float)NP, cy = rs2[0] / (float)NP;
    float l = fmaxf(cx - 12.f, 0.f);
    float tp = fmaxf(cy - 12.f, 0.f);
    out[b * 4 + 0] = l;
    out[b * 4 + 1] = tp;
    out[b * 4 + 2] = fminf(l + 24.f, 64.f);
    out[b * 4 + 3] = fminf(tp + 24.f, 64.f);
  }
}

extern "C" void kernel_launch(void* const* d_in, const int* in_sizes, int n_in,
                              void* d_out, int out_size, void* d_ws, size_t ws_size,
                              hipStream_t stream) {
  const float* patch_x = (const float*)d_in[0];
  const float* x = (const float*)d_in[1];
  float* out = (float*)d_out;
  char* ws = (char*)d_ws;

  float* inv_src = (float*)(ws + 0);                       //    73,728 B
  __hip_bfloat16* srcT = (__hip_bfloat16*)(ws + 73728);    // 18,874,368 B
  float* partials = (float*)(ws + 18948096);               //  9,437,184 B

  norms_kernel<<<dim3((NB * NP + 255) / 256), 256, 0, stream>>>(patch_x, inv_src, NP, NB * NP);
  transpose_kernel<<<dim3(NP / 64, NC / 64, NB), 256, 0, stream>>>(patch_x, inv_src, srcT, NP);
  affinity_kernel<<<dim3(NB * 64), 256, 0, stream>>>(srcT, x, partials);
  finalize_kernel<<<NB, 256, 0, stream>>>(partials, out);
}

// Round 5
// 179.813 us; speedup vs baseline: 1.3496x; 1.3496x over previous
//
#include <hip/hip_runtime.h>
#include <hip/hip_bf16.h>
#include <stdint.h>

#define NB 32
#define NC 512
#define NP 576
#define NN 4096
#define APANEL 589824u   // NP*NC*2 bytes per batch
#define ATILE 36864u     // NP*32*2 bytes per k-tile

typedef __attribute__((ext_vector_type(8))) short short8;
typedef __attribute__((ext_vector_type(4))) float floatx4;

static __device__ __forceinline__ short f2bf(float f) {
  union { __hip_bfloat16 h; short s; } u;
  u.h = __float2bfloat16(f);
  return u.s;
}

#define GLOAD_F32(dst, voff, sbase) \
  asm volatile("global_load_dword %0, %1, %2" : "=v"(dst) : "v"(voff), "s"(sbase))
#define GLOAD_B128(dst, voff, sbase) \
  asm volatile("global_load_dwordx4 %0, %1, %2" : "=v"(dst) : "v"(voff), "s"(sbase))
#define DSWRITE_B128(addr, data) \
  asm volatile("ds_write_b128 %0, %1" :: "v"(addr), "v"(data))
#define WAIT_VMCNT(N) asm volatile("s_waitcnt vmcnt(" #N ")" ::: "memory")
#define WAIT_LGKM0    asm volatile("s_waitcnt lgkmcnt(0)" ::: "memory")
#define SBAR() do { asm volatile("" ::: "memory"); __builtin_amdgcn_s_barrier(); asm volatile("" ::: "memory"); } while (0)
#define SCHEDBAR() __builtin_amdgcn_sched_barrier(0)

// ---------------- K1: inverse L2 norms over channel dim (patch only) ----------------
__global__ void norms_kernel(const float* __restrict__ in, float* __restrict__ invn,
                             int nsp, int total) {
  int idx = blockIdx.x * 256 + threadIdx.x;
  if (idx >= total) return;
  int b = idx / nsp, sp = idx - b * nsp;
  const float* p = in + (size_t)b * NC * nsp + sp;
  float s = 0.f;
#pragma unroll 8
  for (int c = 0; c < NC; ++c) { float v = p[(size_t)c * nsp]; s = fmaf(v, v, s); }
  invn[idx] = 1.0f / fmaxf(sqrtf(s), 1e-12f);
}

// ---------------- K2: patch [C][P] -> MFMA-native fragment-tiled A2, scale, bf16 ----
// A2 layout: byte = b*APANEL + kt*ATILE + (p>>4)*1024 + g*256 + (p&15)*16 + e*2
// where c = kt*32 + g*8 + e.  A wave's fragment load is then base + lane*16,
// fully contiguous (lane = g*16 + l15).
__global__ void transpose_kernel(const float* __restrict__ in, const float* __restrict__ invn,
                                 __hip_bfloat16* __restrict__ out, int nsp) {
  __shared__ float tile[64][65];
  int b = blockIdx.z, c0 = blockIdx.y * 64, p0 = blockIdx.x * 64;
  int tx = threadIdx.x & 63, ty = threadIdx.x >> 6;
  const float* src = in + ((size_t)b * NC + c0) * nsp + p0;
#pragma unroll
  for (int r = ty; r < 64; r += 4) tile[r][tx] = src[(size_t)r * nsp + tx];
  __syncthreads();
  int p_local = threadIdx.x & 63;
  int p = p0 + p_local;
  float iv = invn[b * nsp + p];
  char* dst = (char*)out + (size_t)b * APANEL
            + (uint32_t)(p >> 4) * 1024u + (uint32_t)(p & 15) * 16u;
#pragma unroll
  for (int q = threadIdx.x >> 6; q < 8; q += 4) {
    int c_local = q * 8;
    int c_global = c0 + c_local;
    short8 v;
#pragma unroll
    for (int e = 0; e < 8; ++e) v[e] = f2bf(tile[c_local + e][p_local] * iv);
    uint32_t kt = (uint32_t)c_global >> 5, g = ((uint32_t)c_global >> 3) & 3u;
    *(short8*)(dst + kt * ATILE + g * 256u) = v;
  }
}

// ---------------- K3: fused GEMM + softmax-reduction ----------------
// Round-3 pipeline (no spills), but A loads now hit the fragment-tiled A2:
// each issueA instruction reads 1 KB contiguous (64 lanes x 16 B).
__global__ __launch_bounds__(256, 2)
void affinity_kernel(const __hip_bfloat16* __restrict__ srcT,
                     const float* __restrict__ x,
                     float* __restrict__ partials) {
  const int bid = blockIdx.x;
  const int T = (bid & 7) * 256 + (bid >> 3);   // bijective XCD swizzle (2048 = 8*256)
  const int b = T >> 6, jc = T & 63;
  const int tid = threadIdx.x, lane = tid & 63, w = tid >> 6;
  const int g = lane >> 4, l15 = lane & 15;

  __shared__ __align__(16) char Bl[2][4096];
  __shared__ float red[4][64];
  __shared__ float invd[64];

  const uint64_t sA = (uint64_t)(uintptr_t)srcT;
  const uint64_t sX = (uint64_t)(uintptr_t)x;

  // A2: base + kt*ATILE + (w*9+mi)*1024 + lane*16
  const uint32_t vAbase = (uint32_t)b * APANEL + (uint32_t)(w * 9) * 1024u
                        + (uint32_t)lane * 16u;
  // G: k-row = w*8 + r, j = jc*64 + lane
  const uint32_t vGbase = (uint32_t)(b * NC + w * 8) * (uint32_t)(NN * 4)
                        + (uint32_t)(jc * 64 + lane) * 4u;

  const uint32_t ldsbase = (uint32_t)(uintptr_t)(&Bl[0][0]);
  const uint32_t wraddr = ldsbase + (uint32_t)w * 1024u + (uint32_t)lane * 16u;

  floatx4 acc[9][4];
#pragma unroll
  for (int mi = 0; mi < 9; ++mi)
#pragma unroll
    for (int ni = 0; ni < 4; ++ni) acc[mi][ni] = (floatx4){0.f, 0.f, 0.f, 0.f};

  short8 af[9];
  float GA[8], GB[8];
  float sq = 0.f;

  auto issueA = [&](int t) {
#pragma unroll
    for (int mi = 0; mi < 9; ++mi) {
      uint32_t v = vAbase + (uint32_t)mi * 1024u + (uint32_t)t * ATILE;
      GLOAD_B128(af[mi], v, sA);
    }
  };
  auto issueG = [&](int t, float (&Gv)[8]) {
#pragma unroll
    for (int r = 0; r < 8; ++r) {
      uint32_t v = vGbase + (uint32_t)r * (uint32_t)(NN * 4) + (uint32_t)t * (32u * NN * 4u);
      GLOAD_F32(Gv[r], v, sX);
    }
  };
  auto cvtWrite = [&](float (&Gv)[8], uint32_t slotoff) {
    short8 bf;
#pragma unroll
    for (int r = 0; r < 8; ++r) {
      sq = fmaf(Gv[r], Gv[r], sq);
      bf[r] = f2bf(Gv[r]);
    }
    DSWRITE_B128(wraddr + slotoff, bf);
  };
  auto mfmaStep = [&](uint32_t slotoff) {
#pragma unroll
    for (int ni = 0; ni < 4; ++ni) {
      short8 bfr = *(const short8*)(&Bl[0][0] + slotoff + (uint32_t)g * 1024u
                                    + (uint32_t)ni * 256u + (uint32_t)l15 * 16u);
#pragma unroll
      for (int mi = 0; mi < 9; ++mi)
        acc[mi][ni] = __builtin_amdgcn_mfma_f32_16x16x32_bf16(af[mi], bfr, acc[mi][ni], 0, 0, 0);
    }
  };

  // ---- prologue: G0 -> GA, G1 -> GB; write buf0 ----
  issueG(0, GA);
  issueG(1, GB);
  WAIT_VMCNT(8); SCHEDBAR();      // GA done, GB in flight
  cvtWrite(GA, 0);
  WAIT_LGKM0;
  SBAR();

  // ---- main loop: iters 0..13 (double-stepped) ----
#pragma unroll 1
  for (int kt = 0; kt < 14; kt += 2) {
    // even half: consume tile kt (buf0), write tile kt+1 (buf1)
    issueA(kt);
    issueG(kt + 2, GA);
    WAIT_VMCNT(8); SCHEDBAR();    // drains G[kt+1](GB) + A; G[kt+2] in flight
    cvtWrite(GB, 4096u);
    mfmaStep(0u);
    WAIT_LGKM0;
    SBAR();
    // odd half: consume tile kt+1 (buf1), write tile kt+2 (buf0)
    issueA(kt + 1);
    issueG(kt + 3, GB);
    WAIT_VMCNT(8); SCHEDBAR();    // drains G[kt+2](GA) + A; G[kt+3] in flight
    cvtWrite(GA, 0u);
    mfmaStep(4096u);
    WAIT_LGKM0;
    SBAR();
  }
  // ---- tail: iter 14 ----
  issueA(14);
  WAIT_VMCNT(0); SCHEDBAR();      // drains G15(GB) + A
  cvtWrite(GB, 4096u);
  mfmaStep(0u);
  WAIT_LGKM0;
  SBAR();
  // ---- tail: iter 15 ----
  issueA(15);
  WAIT_VMCNT(0); SCHEDBAR();
  mfmaStep(4096u);

  // ---- dst inv-norms from in-loop fp32 sumsq (lane's column j = lane) ----
  __syncthreads();
  red[w][lane] = sq;
  __syncthreads();
  if (tid < 64)
    invd[tid] = rsqrtf(fmaxf(red[0][tid] + red[1][tid] + red[2][tid] + red[3][tid], 1e-24f));
  __syncthreads();

  float iv[4], cxj[4];
#pragma unroll
  for (int ni = 0; ni < 4; ++ni) {
    iv[ni] = invd[ni * 16 + l15];
    cxj[ni] = (float)(ni * 16 + l15) + 0.5f;   // cx = (j & 63) + 0.5
  }

  // ---- exp + weighted reduction (cy = jc + 0.5 block-uniform) ----
#pragma unroll
  for (int mi = 0; mi < 9; ++mi) {
    float s[4] = {0.f, 0.f, 0.f, 0.f}, sx[4] = {0.f, 0.f, 0.f, 0.f};
#pragma unroll
    for (int ni = 0; ni < 4; ++ni)
#pragma unroll
      for (int r = 0; r < 4; ++r) {
        float p = __expf(acc[mi][ni][r] * iv[ni]);
        s[r] += p;
        sx[r] = fmaf(p, cxj[ni], sx[r]);
      }
#pragma unroll
    for (int r = 0; r < 4; ++r) {
#pragma unroll
      for (int m = 1; m < 16; m <<= 1) {
        s[r] += __shfl_xor(s[r], m);
        sx[r] += __shfl_xor(sx[r], m);
      }
    }
    if (l15 == 0) {
#pragma unroll
      for (int r = 0; r < 4; ++r) {
        int row = w * 144 + mi * 16 + g * 4 + r;
        float* o = partials + ((size_t)(b * NP + row) * 64 + jc) * 2;
        o[0] = s[r];
        o[1] = sx[r];
      }
    }
  }
}

// ---------------- K4: finalize ----------------
__global__ void finalize_kernel(const float* __restrict__ partials, float* __restrict__ out) {
  int b = blockIdx.x;
  int t = threadIdx.x;
  float sxt = 0.f, syt = 0.f;
  for (int i = t; i < NP; i += 256) {
    const float* p = partials + ((size_t)(b * NP + i) * 64) * 2;
    float s = 0.f, sx = 0.f, sy = 0.f;
#pragma unroll
    for (int jc2 = 0; jc2 < 64; ++jc2) {
      float ss = p[jc2 * 2];
      s += ss;
      sx += p[jc2 * 2 + 1];
      sy = fmaf(ss, (float)jc2 + 0.5f, sy);
    }
    sxt += sx / s;
    syt += sy / s;
  }
  __shared__ float rs[256], rs2[256];
  rs[t] = sxt; rs2[t] = syt;
  __syncthreads();
  for (int o = 128; o > 0; o >>= 1) {
    if (t < o) { rs[t] += rs[t + o]; rs2[t] += rs2[t + o]; }
    __syncthreads();
  }
  if (t == 0) {
    float cx = rs[0] / (float)NP, cy = rs2[0] / (float)NP;
    float l = fmaxf(cx - 12.f, 0.f);
    float tp = fmaxf(cy - 12.f, 0.f);
    out[b * 4 + 0] = l;
    out[b * 4 + 1] = tp;
    out[b * 4 + 2] = fminf(l + 24.f, 64.f);
    out[b * 4 + 3] = fminf(tp + 24.f, 64.f);
  }
}

extern "C" void kernel_launch(void* const* d_in, const int* in_sizes, int n_in,
                              void* d_out, int out_size, void* d_ws, size_t ws_size,
                              hipStream_t stream) {
  const float* patch_x = (const float*)d_in[0];
  const float* x = (const float*)d_in[1];
  float* out = (float*)d_out;
  char* ws = (char*)d_ws;

  float* inv_src = (float*)(ws + 0);                       //    73,728 B
  __hip_bfloat16* srcT = (__hip_bfloat16*)(ws + 73728);    // 18,874,368 B (A2)
  float* partials = (float*)(ws + 18948096);               //  9,437,184 B

  norms_kernel<<<dim3((NB * NP + 255) / 256), 256, 0, stream>>>(patch_x, inv_src, NP, NB * NP);
  transpose_kernel<<<dim3(NP / 64, NC / 64, NB), 256, 0, stream>>>(patch_x, inv_src, srcT, NP);
  affinity_kernel<<<dim3(NB * 64), 256, 0, stream>>>(srcT, x, partials);
  finalize_kernel<<<NB, 256, 0, stream>>>(partials, out);
}

// Round 6
// 175.236 us; speedup vs baseline: 1.3849x; 1.0261x over previous
//
#include <hip/hip_runtime.h>
#include <hip/hip_bf16.h>
#include <stdint.h>

#define NB 32
#define NC 512
#define NP 576
#define NN 4096
#define APANEL 589824u   // NP*NC*2 bytes per batch
#define ATILE 36864u     // NP*32*2 bytes per k-tile

typedef __attribute__((ext_vector_type(8))) short short8;
typedef __attribute__((ext_vector_type(4))) float floatx4;

static __device__ __forceinline__ short f2bf(float f) {
  union { __hip_bfloat16 h; short s; } u;
  u.h = __float2bfloat16(f);
  return u.s;
}

#define GLOAD_F32(dst, voff, sbase) \
  asm volatile("global_load_dword %0, %1, %2" : "=v"(dst) : "v"(voff), "s"(sbase))
#define GLOAD_B128(dst, voff, sbase) \
  asm volatile("global_load_dwordx4 %0, %1, %2" : "=v"(dst) : "v"(voff), "s"(sbase))
#define DSWRITE_B128(addr, data) \
  asm volatile("ds_write_b128 %0, %1" :: "v"(addr), "v"(data))
#define WAIT_VMCNT(N) asm volatile("s_waitcnt vmcnt(" #N ")" ::: "memory")
#define WAIT_LGKM0    asm volatile("s_waitcnt lgkmcnt(0)" ::: "memory")
#define SBAR() do { asm volatile("" ::: "memory"); __builtin_amdgcn_s_barrier(); asm volatile("" ::: "memory"); } while (0)
#define SCHEDBAR() __builtin_amdgcn_sched_barrier(0)

// ---------------- K1: inverse L2 norms over channel dim (patch only) ----------------
__global__ void norms_kernel(const float* __restrict__ in, float* __restrict__ invn,
                             int nsp, int total) {
  int idx = blockIdx.x * 256 + threadIdx.x;
  if (idx >= total) return;
  int b = idx / nsp, sp = idx - b * nsp;
  const float* p = in + (size_t)b * NC * nsp + sp;
  float s = 0.f;
#pragma unroll 8
  for (int c = 0; c < NC; ++c) { float v = p[(size_t)c * nsp]; s = fmaf(v, v, s); }
  invn[idx] = 1.0f / fmaxf(sqrtf(s), 1e-12f);
}

// ---------------- K2: patch [C][P] -> MFMA-native fragment-tiled A2, scale, bf16 ----
// A2 layout: byte = b*APANEL + kt*ATILE + (p>>4)*1024 + g*256 + (p&15)*16 + e*2
// where c = kt*32 + g*8 + e.  A wave's fragment load is then base + lane*16.
__global__ void transpose_kernel(const float* __restrict__ in, const float* __restrict__ invn,
                                 __hip_bfloat16* __restrict__ out, int nsp) {
  __shared__ float tile[64][65];
  int b = blockIdx.z, c0 = blockIdx.y * 64, p0 = blockIdx.x * 64;
  int tx = threadIdx.x & 63, ty = threadIdx.x >> 6;
  const float* src = in + ((size_t)b * NC + c0) * nsp + p0;
#pragma unroll
  for (int r = ty; r < 64; r += 4) tile[r][tx] = src[(size_t)r * nsp + tx];
  __syncthreads();
  int p_local = threadIdx.x & 63;
  int p = p0 + p_local;
  float iv = invn[b * nsp + p];
  char* dst = (char*)out + (size_t)b * APANEL
            + (uint32_t)(p >> 4) * 1024u + (uint32_t)(p & 15) * 16u;
#pragma unroll
  for (int q = threadIdx.x >> 6; q < 8; q += 4) {
    int c_local = q * 8;
    int c_global = c0 + c_local;
    short8 v;
#pragma unroll
    for (int e = 0; e < 8; ++e) v[e] = f2bf(tile[c_local + e][p_local] * iv);
    uint32_t kt = (uint32_t)c_global >> 5, g = ((uint32_t)c_global >> 3) & 3u;
    *(short8*)(dst + kt * ATILE + g * 256u) = v;
  }
}

// ---------------- K3: fused GEMM + softmax-reduction ----------------
// Per iter t: vmcnt(8)[A(t) home] -> MFMA(t) -> issueA(t+1) -> issueG(t+2)
// -> vmcnt(17)[retire G(t+1) only] -> cvt/ds_write -> lgkm0 -> barrier.
// A prefetch depth 1 (single af buffer: issue AFTER consume), G depth 2.
__global__ __launch_bounds__(256, 2)
void affinity_kernel(const __hip_bfloat16* __restrict__ srcT,
                     const float* __restrict__ x,
                     float* __restrict__ partials) {
  const int bid = blockIdx.x;
  const int T = (bid & 7) * 256 + (bid >> 3);   // bijective XCD swizzle (2048 = 8*256)
  const int b = T >> 6, jc = T & 63;
  const int tid = threadIdx.x, lane = tid & 63, w = tid >> 6;
  const int g = lane >> 4, l15 = lane & 15;

  __shared__ __align__(16) char Bl[2][4096];
  __shared__ float red[4][64];
  __shared__ float invd[64];

  const uint64_t sA = (uint64_t)(uintptr_t)srcT;
  const uint64_t sX = (uint64_t)(uintptr_t)x;

  // A2: base + kt*ATILE + (w*9+mi)*1024 + lane*16
  const uint32_t vAbase = (uint32_t)b * APANEL + (uint32_t)(w * 9) * 1024u
                        + (uint32_t)lane * 16u;
  // G: k-row = w*8 + r, j = jc*64 + lane
  const uint32_t vGbase = (uint32_t)(b * NC + w * 8) * (uint32_t)(NN * 4)
                        + (uint32_t)(jc * 64 + lane) * 4u;

  const uint32_t ldsbase = (uint32_t)(uintptr_t)(&Bl[0][0]);
  const uint32_t wraddr = ldsbase + (uint32_t)w * 1024u + (uint32_t)lane * 16u;

  floatx4 acc[9][4];
#pragma unroll
  for (int mi = 0; mi < 9; ++mi)
#pragma unroll
    for (int ni = 0; ni < 4; ++ni) acc[mi][ni] = (floatx4){0.f, 0.f, 0.f, 0.f};

  short8 af[9];
  float GA[8], GB[8];
  float sq = 0.f;

  auto issueA = [&](int t) {
#pragma unroll
    for (int mi = 0; mi < 9; ++mi) {
      uint32_t v = vAbase + (uint32_t)mi * 1024u + (uint32_t)t * ATILE;
      GLOAD_B128(af[mi], v, sA);
    }
  };
  auto issueG = [&](int t, float (&Gv)[8]) {
#pragma unroll
    for (int r = 0; r < 8; ++r) {
      uint32_t v = vGbase + (uint32_t)r * (uint32_t)(NN * 4) + (uint32_t)t * (32u * NN * 4u);
      GLOAD_F32(Gv[r], v, sX);
    }
  };
  auto cvtWrite = [&](float (&Gv)[8], uint32_t slotoff) {
    short8 bf;
#pragma unroll
    for (int r = 0; r < 8; ++r) {
      sq = fmaf(Gv[r], Gv[r], sq);
      bf[r] = f2bf(Gv[r]);
    }
    DSWRITE_B128(wraddr + slotoff, bf);
  };
  auto mfmaStep = [&](uint32_t slotoff) {
#pragma unroll
    for (int ni = 0; ni < 4; ++ni) {
      short8 bfr = *(const short8*)(&Bl[0][0] + slotoff + (uint32_t)g * 1024u
                                    + (uint32_t)ni * 256u + (uint32_t)l15 * 16u);
#pragma unroll
      for (int mi = 0; mi < 9; ++mi)
        acc[mi][ni] = __builtin_amdgcn_mfma_f32_16x16x32_bf16(af[mi], bfr, acc[mi][ni], 0, 0, 0);
    }
  };

  // ---- prologue: issue order G0, A0, G1 so loop-top vmcnt(8) retires exactly A0 ----
  issueG(0, GB);
  issueA(0);
  issueG(1, GA);
  WAIT_VMCNT(17); SCHEDBAR();     // retire G0 (GB); queue: A0[9] + G1[8]
  cvtWrite(GB, 0u);
  WAIT_LGKM0;
  SBAR();

  // ---- main loop: tiles 0..13, unrolled x2 ----
#pragma unroll 1
  for (int t = 0; t < 14; t += 2) {
    // even tile t: consume buf0 with A(t)
    WAIT_VMCNT(8); SCHEDBAR();    // retire A(t); queue: G(t+1)(GA)[8]
    mfmaStep(0u);
    issueA(t + 1);                // af free after mfmaStep
    issueG(t + 2, GB);            // queue: G(t+1)[8] + A(t+1)[9] + G(t+2)[8]
    WAIT_VMCNT(17); SCHEDBAR();   // retire G(t+1) (GA) only
    cvtWrite(GA, 4096u);
    WAIT_LGKM0;
    SBAR();
    // odd tile t+1: consume buf1 with A(t+1)
    WAIT_VMCNT(8); SCHEDBAR();    // retire A(t+1); queue: G(t+2)(GB)[8]
    mfmaStep(4096u);
    issueA(t + 2);
    issueG(t + 3, GA);
    WAIT_VMCNT(17); SCHEDBAR();   // retire G(t+2) (GB) only
    cvtWrite(GB, 0u);
    WAIT_LGKM0;
    SBAR();
  }
  // ---- tail tile 14 (buf0): G15 in GA is in flight; no G16 ----
  WAIT_VMCNT(8); SCHEDBAR();      // retire A14; queue: G15[8]
  mfmaStep(0u);
  issueA(15);                     // queue: G15[8] + A15[9]
  WAIT_VMCNT(9); SCHEDBAR();      // retire G15 (GA)
  cvtWrite(GA, 4096u);
  WAIT_LGKM0;
  SBAR();
  // ---- tail tile 15 (buf1) ----
  WAIT_VMCNT(0); SCHEDBAR();      // retire A15
  mfmaStep(4096u);

  // ---- dst inv-norms from in-loop fp32 sumsq (lane's column j = lane) ----
  __syncthreads();
  red[w][lane] = sq;
  __syncthreads();
  if (tid < 64)
    invd[tid] = rsqrtf(fmaxf(red[0][tid] + red[1][tid] + red[2][tid] + red[3][tid], 1e-24f))
              * 1.44269504088896340736f;   // fold log2(e): exp(z) = exp2(z*log2e)
  __syncthreads();

  float iv[4], cxj[4];
#pragma unroll
  for (int ni = 0; ni < 4; ++ni) {
    iv[ni] = invd[ni * 16 + l15];
    cxj[ni] = (float)(ni * 16 + l15) + 0.5f;   // cx = (j & 63) + 0.5
  }

  // ---- exp + weighted reduction (cy = jc + 0.5 block-uniform) ----
#pragma unroll
  for (int mi = 0; mi < 9; ++mi) {
    float s[4] = {0.f, 0.f, 0.f, 0.f}, sx[4] = {0.f, 0.f, 0.f, 0.f};
#pragma unroll
    for (int ni = 0; ni < 4; ++ni)
#pragma unroll
      for (int r = 0; r < 4; ++r) {
        float p = exp2f(acc[mi][ni][r] * iv[ni]);
        s[r] += p;
        sx[r] = fmaf(p, cxj[ni], sx[r]);
      }
#pragma unroll
    for (int r = 0; r < 4; ++r) {
#pragma unroll
      for (int m = 1; m < 16; m <<= 1) {
        s[r] += __shfl_xor(s[r], m);
        sx[r] += __shfl_xor(sx[r], m);
      }
    }
    if (l15 == 0) {
#pragma unroll
      for (int r = 0; r < 4; ++r) {
        int row = w * 144 + mi * 16 + g * 4 + r;
        float* o = partials + ((size_t)(b * NP + row) * 64 + jc) * 2;
        o[0] = s[r];
        o[1] = sx[r];
      }
    }
  }
}

// ---------------- K4: finalize ----------------
__global__ void finalize_kernel(const float* __restrict__ partials, float* __restrict__ out) {
  int b = blockIdx.x;
  int t = threadIdx.x;
  float sxt = 0.f, syt = 0.f;
  for (int i = t; i < NP; i += 256) {
    const float* p = partials + ((size_t)(b * NP + i) * 64) * 2;
    float s = 0.f, sx = 0.f, sy = 0.f;
#pragma unroll
    for (int jc2 = 0; jc2 < 64; ++jc2) {
      float ss = p[jc2 * 2];
      s += ss;
      sx += p[jc2 * 2 + 1];
      sy = fmaf(ss, (float)jc2 + 0.5f, sy);
    }
    sxt += sx / s;
    syt += sy / s;
  }
  __shared__ float rs[256], rs2[256];
  rs[t] = sxt; rs2[t] = syt;
  __syncthreads();
  for (int o = 128; o > 0; o >>= 1) {
    if (t < o) { rs[t] += rs[t + o]; rs2[t] += rs2[t + o]; }
    __syncthreads();
  }
  if (t == 0) {
    float cx = rs[0] / (float)NP, cy = rs2[0] / (float)NP;
    float l = fmaxf(cx - 12.f, 0.f);
    float tp = fmaxf(cy - 12.f, 0.f);
    out[b * 4 + 0] = l;
    out[b * 4 + 1] = tp;
    out[b * 4 + 2] = fminf(l + 24.f, 64.f);
    out[b * 4 + 3] = fminf(tp + 24.f, 64.f);
  }
}

extern "C" void kernel_launch(void* const* d_in, const int* in_sizes, int n_in,
                              void* d_out, int out_size, void* d_ws, size_t ws_size,
                              hipStream_t stream) {
  const float* patch_x = (const float*)d_in[0];
  const float* x = (const float*)d_in[1];
  float* out = (float*)d_out;
  char* ws = (char*)d_ws;

  float* inv_src = (float*)(ws + 0);                       //    73,728 B
  __hip_bfloat16* srcT = (__hip_bfloat16*)(ws + 73728);    // 18,874,368 B (A2)
  float* partials = (float*)(ws + 18948096);               //  9,437,184 B

  norms_kernel<<<dim3((NB * NP + 255) / 256), 256, 0, stream>>>(patch_x, inv_src, NP, NB * NP);
  transpose_kernel<<<dim3(NP / 64, NC / 64, NB), 256, 0, stream>>>(patch_x, inv_src, srcT, NP);
  affinity_kernel<<<dim3(NB * 64), 256, 0, stream>>>(srcT, x, partials);
  finalize_kernel<<<NB, 256, 0, stream>>>(partials, out);
}

// Round 7
// 164.855 us; speedup vs baseline: 1.4721x; 1.0630x over previous
//
#include <hip/hip_runtime.h>
#include <hip/hip_bf16.h>
#include <stdint.h>

#define NB 32
#define NC 512
#define NP 576
#define NN 4096
#define APANEL8 294912u  // NP*NC bytes (fp8)
#define ATILE8 18432u    // NP*32 bytes per k-tile

typedef __attribute__((ext_vector_type(4))) float floatx4;

#define GLOAD_F32(dst, voff, sbase) \
  asm volatile("global_load_dword %0, %1, %2" : "=v"(dst) : "v"(voff), "s"(sbase))
#define GLOAD_B64(dst, voff, sbase) \
  asm volatile("global_load_dwordx2 %0, %1, %2" : "=v"(dst) : "v"(voff), "s"(sbase))
#define DSWRITE_B64(addr, data) \
  asm volatile("ds_write_b64 %0, %1" :: "v"(addr), "v"(data))
#define WAIT_VMCNT(N) asm volatile("s_waitcnt vmcnt(" #N ")" ::: "memory")
#define WAIT_LGKM0    asm volatile("s_waitcnt lgkmcnt(0)" ::: "memory")
#define SBAR() __builtin_amdgcn_s_barrier()
#define SCHEDBAR() __builtin_amdgcn_sched_barrier(0)

// ---------------- K1: inverse L2 norms over channel dim (patch only) ----------------
__global__ void norms_kernel(const float* __restrict__ in, float* __restrict__ invn,
                             int nsp, int total) {
  int idx = blockIdx.x * 256 + threadIdx.x;
  if (idx >= total) return;
  int b = idx / nsp, sp = idx - b * nsp;
  const float* p = in + (size_t)b * NC * nsp + sp;
  float s = 0.f;
#pragma unroll 8
  for (int c = 0; c < NC; ++c) { float v = p[(size_t)c * nsp]; s = fmaf(v, v, s); }
  invn[idx] = 1.0f / fmaxf(sqrtf(s), 1e-12f);
}

// ---------------- K2: patch [C][P] -> fp8 fragment-tiled A2, scale ----------------
// A2 byte = b*APANEL8 + kt*ATILE8 + (p>>4)*512 + g*128 + (p&15)*8 + e,
// where c = kt*32 + g*8 + e. Wave fragment load = base + lane*8 (contiguous).
__global__ void transpose_kernel(const float* __restrict__ in, const float* __restrict__ invn,
                                 uint8_t* __restrict__ out, int nsp) {
  __shared__ float tile[64][65];
  int b = blockIdx.z, c0 = blockIdx.y * 64, p0 = blockIdx.x * 64;
  int tx = threadIdx.x & 63, ty = threadIdx.x >> 6;
  const float* src = in + ((size_t)b * NC + c0) * nsp + p0;
#pragma unroll
  for (int r = ty; r < 64; r += 4) tile[r][tx] = src[(size_t)r * nsp + tx];
  __syncthreads();
  int p = p0 + tx;
  float iv = invn[b * nsp + p];
  char* dst = (char*)out + (size_t)b * APANEL8
            + (uint32_t)(p >> 4) * 512u + (uint32_t)(p & 15) * 8u;
#pragma unroll
  for (int q = ty; q < 8; q += 4) {
    int c_local = q * 8, c_global = c0 + c_local;
    float f[8];
#pragma unroll
    for (int e = 0; e < 8; ++e) f[e] = tile[c_local + e][tx] * iv;
    int lo = 0, hi = 0;
    lo = __builtin_amdgcn_cvt_pk_fp8_f32(f[0], f[1], lo, false);
    lo = __builtin_amdgcn_cvt_pk_fp8_f32(f[2], f[3], lo, true);
    hi = __builtin_amdgcn_cvt_pk_fp8_f32(f[4], f[5], hi, false);
    hi = __builtin_amdgcn_cvt_pk_fp8_f32(f[6], f[7], hi, true);
    union { int i2[2]; long l; } u; u.i2[0] = lo; u.i2[1] = hi;
    uint32_t kt = (uint32_t)c_global >> 5, gg = ((uint32_t)c_global >> 3) & 3u;
    *(long*)(dst + kt * ATILE8 + gg * 128u) = u.l;
  }
}

// ---------------- K3: fused GEMM + softmax-reduction (fp8, 12 waves) ----------------
// Block: 768 thr. Wave w owns rows 48w..48w+47 (acc[3][4], 48 AGPR).
// Waves 0-3 stage B (k-rows 8w..8w+7 of the 32-row k-tile -> fp8 -> LDS k-group w).
// Depth-2 A (afA/afB) and depth-2 G pipelines with counted per-role vmcnt.
__global__ __launch_bounds__(768, 3)
void affinity_kernel(const uint8_t* __restrict__ A2,
                     const float* __restrict__ x,
                     float* __restrict__ partials) {
  const int bid = blockIdx.x;
  const int T = (bid & 7) * 256 + (bid >> 3);   // bijective XCD swizzle (2048 = 8*256)
  const int b = T >> 6, jc = T & 63;
  const int tid = threadIdx.x, lane = tid & 63, w = tid >> 6;
  const int g = lane >> 4, l15 = lane & 15;
  const bool stager = (w < 4);

  __shared__ __align__(16) char Bl[2][2048];
  __shared__ float red[4][64];
  __shared__ float invd[64];

  const uint64_t sA = (uint64_t)(uintptr_t)A2;
  const uint64_t sX = (uint64_t)(uintptr_t)x;

  // A2: rowgroups w*3+mi; per-lane +lane*8 (= g*128 + l15*8)
  const uint32_t vAbase = (uint32_t)b * APANEL8 + (uint32_t)(w * 3) * 512u
                        + (uint32_t)lane * 8u;
  // G (stagers): k-row = w*8 + r, j = jc*64 + lane
  const uint32_t vGbase = (uint32_t)(b * NC + w * 8) * (uint32_t)(NN * 4)
                        + (uint32_t)(jc * 64 + lane) * 4u;

  const uint32_t ldsbase = (uint32_t)(uintptr_t)(&Bl[0][0]);
  const uint32_t wraddr = ldsbase + (uint32_t)w * 512u + (uint32_t)lane * 8u;

  floatx4 acc[3][4];
#pragma unroll
  for (int mi = 0; mi < 3; ++mi)
#pragma unroll
    for (int ni = 0; ni < 4; ++ni) acc[mi][ni] = (floatx4){0.f, 0.f, 0.f, 0.f};

  long afA[3], afB[3];
  float GA[8], GB[8];
  float sq = 0.f;

  auto issueA = [&](int t, long (&af)[3]) {
#pragma unroll
    for (int mi = 0; mi < 3; ++mi) {
      uint32_t v = vAbase + (uint32_t)mi * 512u + (uint32_t)t * ATILE8;
      GLOAD_B64(af[mi], v, sA);
    }
  };
  auto issueG = [&](int t, float (&Gv)[8]) {
#pragma unroll
    for (int r = 0; r < 8; ++r) {
      uint32_t v = vGbase + (uint32_t)r * (uint32_t)(NN * 4) + (uint32_t)t * (32u * NN * 4u);
      GLOAD_F32(Gv[r], v, sX);
    }
  };
  auto cvtWrite = [&](float (&Gv)[8], uint32_t slotoff) {
#pragma unroll
    for (int r = 0; r < 8; ++r) sq = fmaf(Gv[r], Gv[r], sq);
    int lo = 0, hi = 0;
    lo = __builtin_amdgcn_cvt_pk_fp8_f32(Gv[0], Gv[1], lo, false);
    lo = __builtin_amdgcn_cvt_pk_fp8_f32(Gv[2], Gv[3], lo, true);
    hi = __builtin_amdgcn_cvt_pk_fp8_f32(Gv[4], Gv[5], hi, false);
    hi = __builtin_amdgcn_cvt_pk_fp8_f32(Gv[6], Gv[7], hi, true);
    union { int i2[2]; long l; } u; u.i2[0] = lo; u.i2[1] = hi;
    DSWRITE_B64(wraddr + slotoff, u.l);
  };
  auto mfmaStep = [&](uint32_t slotoff, long (&af)[3]) {
    __builtin_amdgcn_s_setprio(1);
#pragma unroll
    for (int ni = 0; ni < 4; ++ni) {
      long bfr = *(const long*)(&Bl[0][0] + slotoff + (uint32_t)g * 512u
                                + (uint32_t)ni * 128u + (uint32_t)l15 * 8u);
#pragma unroll
      for (int mi = 0; mi < 3; ++mi)
        acc[mi][ni] = __builtin_amdgcn_mfma_f32_16x16x32_fp8_fp8(af[mi], bfr, acc[mi][ni], 0, 0, 0);
    }
    __builtin_amdgcn_s_setprio(0);
  };

  // ---- prologue ----
  if (stager) {
    issueG(0, GB);
    issueA(0, afA);
    issueG(1, GA);
    issueA(1, afB);
    WAIT_VMCNT(14); SCHEDBAR();   // retire G0; queue: A0[3] G1[8] A1[3]
    cvtWrite(GB, 0u);             // B(0) -> buf0
    WAIT_LGKM0;
  } else {
    issueA(0, afA);
    issueA(1, afB);               // queue: A0[3] A1[3]
  }
  SBAR();

  // ---- main loop: tiles 0..13, unrolled x2 ----
#pragma unroll 1
  for (int t = 0; t < 14; t += 2) {
    // even tile t: consume buf0, afA
    if (stager) { WAIT_VMCNT(11); } else { WAIT_VMCNT(3); }   // retire A(t)
    SCHEDBAR();
    mfmaStep(0u, afA);
    if (stager) {
      issueG(t + 2, GB);          // queue: G(t+1)[8] A(t+1)[3] G(t+2)[8]
      WAIT_VMCNT(11); SCHEDBAR(); // retire G(t+1) (GA)
      issueA(t + 2, afA);
      cvtWrite(GA, 2048u);        // B(t+1) -> buf1
      WAIT_LGKM0;
    } else {
      issueA(t + 2, afA);
    }
    SBAR();
    // odd tile t+1: consume buf1, afB
    if (stager) { WAIT_VMCNT(11); } else { WAIT_VMCNT(3); }   // retire A(t+1)
    SCHEDBAR();
    mfmaStep(2048u, afB);
    if (stager) {
      issueG(t + 3, GA);
      WAIT_VMCNT(11); SCHEDBAR(); // retire G(t+2) (GB)
      issueA(t + 3, afB);
      cvtWrite(GB, 0u);           // B(t+2) -> buf0
      WAIT_LGKM0;
    } else {
      issueA(t + 3, afB);
    }
    SBAR();
  }
  // ---- tail tile 14 (buf0, afA): G15 in GA in flight; no G16/A16 ----
  if (stager) { WAIT_VMCNT(11); } else { WAIT_VMCNT(3); }     // retire A14
  SCHEDBAR();
  mfmaStep(0u, afA);
  if (stager) {
    WAIT_VMCNT(3); SCHEDBAR();    // retire G15 (GA); keep A15
    cvtWrite(GA, 2048u);          // B(15) -> buf1
    WAIT_LGKM0;
  }
  SBAR();
  // ---- tail tile 15 (buf1, afB) ----
  WAIT_VMCNT(0); SCHEDBAR();      // retire A15
  mfmaStep(2048u, afB);

  // ---- dst inv-norms from in-loop fp32 sumsq ----
  __syncthreads();
  if (stager) red[w][lane] = sq;
  __syncthreads();
  if (tid < 64)
    invd[tid] = rsqrtf(fmaxf(red[0][tid] + red[1][tid] + red[2][tid] + red[3][tid], 1e-24f))
              * 1.44269504088896340736f;   // fold log2(e)
  __syncthreads();

  float iv[4], cxj[4];
#pragma unroll
  for (int ni = 0; ni < 4; ++ni) {
    iv[ni] = invd[ni * 16 + l15];
    cxj[ni] = (float)(ni * 16 + l15) + 0.5f;   // cx = (j & 63) + 0.5
  }

  // ---- exp + weighted reduction (cy = jc + 0.5 block-uniform) ----
#pragma unroll
  for (int mi = 0; mi < 3; ++mi) {
    float s[4] = {0.f, 0.f, 0.f, 0.f}, sx[4] = {0.f, 0.f, 0.f, 0.f};
#pragma unroll
    for (int ni = 0; ni < 4; ++ni)
#pragma unroll
      for (int r = 0; r < 4; ++r) {
        float p = exp2f(acc[mi][ni][r] * iv[ni]);
        s[r] += p;
        sx[r] = fmaf(p, cxj[ni], sx[r]);
      }
#pragma unroll
    for (int r = 0; r < 4; ++r) {
#pragma unroll
      for (int m = 1; m < 16; m <<= 1) {
        s[r] += __shfl_xor(s[r], m);
        sx[r] += __shfl_xor(sx[r], m);
      }
    }
    if (l15 == 0) {
#pragma unroll
      for (int r = 0; r < 4; ++r) {
        int row = w * 48 + mi * 16 + g * 4 + r;
        float* o = partials + ((size_t)(b * NP + row) * 64 + jc) * 2;
        o[0] = s[r];
        o[1] = sx[r];
      }
    }
  }
}

// ---------------- K4: finalize ----------------
__global__ void finalize_kernel(const float* __restrict__ partials, float* __restrict__ out) {
  int b = blockIdx.x;
  int t = threadIdx.x;
  float sxt = 0.f, syt = 0.f;
  for (int i = t; i < NP; i += 256) {
    const float* p = partials + ((size_t)(b * NP + i) * 64) * 2;
    float s = 0.f, sx = 0.f, sy = 0.f;
#pragma unroll
    for (int jc2 = 0; jc2 < 64; ++jc2) {
      float ss = p[jc2 * 2];
      s += ss;
      sx += p[jc2 * 2 + 1];
      sy = fmaf(ss, (float)jc2 + 0.5f, sy);
    }
    sxt += sx / s;
    syt += sy / s;
  }
  __shared__ float rs[256], rs2[256];
  rs[t] = sxt; rs2[t] = syt;
  __syncthreads();
  for (int o = 128; o > 0; o >>= 1) {
    if (t < o) { rs[t] += rs[t + o]; rs2[t] += rs2[t + o]; }
    __syncthreads();
  }
  if (t == 0) {
    float cx = rs[0] / (float)NP, cy = rs2[0] / (float)NP;
    float l = fmaxf(cx - 12.f, 0.f);
    float tp = fmaxf(cy - 12.f, 0.f);
    out[b * 4 + 0] = l;
    out[b * 4 + 1] = tp;
    out[b * 4 + 2] = fminf(l + 24.f, 64.f);
    out[b * 4 + 3] = fminf(tp + 24.f, 64.f);
  }
}

extern "C" void kernel_launch(void* const* d_in, const int* in_sizes, int n_in,
                              void* d_out, int out_size, void* d_ws, size_t ws_size,
                              hipStream_t stream) {
  const float* patch_x = (const float*)d_in[0];
  const float* x = (const float*)d_in[1];
  float* out = (float*)d_out;
  char* ws = (char*)d_ws;

  float* inv_src = (float*)(ws + 0);                  //    73,728 B
  uint8_t* A2 = (uint8_t*)(ws + 73728);               //  9,437,184 B (fp8)
  float* partials = (float*)(ws + 9510912);           //  9,437,184 B

  norms_kernel<<<dim3((NB * NP + 255) / 256), 256, 0, stream>>>(patch_x, inv_src, NP, NB * NP);
  transpose_kernel<<<dim3(NP / 64, NC / 64, NB), 256, 0, stream>>>(patch_x, inv_src, A2, NP);
  affinity_kernel<<<dim3(NB * 64), 768, 0, stream>>>(A2, x, partials);
  finalize_kernel<<<NB, 256, 0, stream>>>(partials, out);
}